// Round 3
// baseline (252.430 us; speedup 1.0000x reference)
//
#include <hip/hip_runtime.h>

// EWMA scan z_t = lam*z_{t-1} + (1-lam)*x_t over [B,L,K], chunk-parallel with
// 128-step warm-up (error <= lam^129 * max|z| ~ 1e-3 << 1.7e-2 threshold).
//
// R4 FAILED: CHUNK 128->32: occupancy 9->33% but FETCH 130->300 MB -> 130us.
// R5 NEUTRAL: K-split 4 (16 waves/CU, traffic back to 1x) -> still 95us,
//     2.8 TB/s, VALUBusy 5.7%, VGPR=24 (compiler folded the pipeline).
//     Diagnosis: 4x waves changed nothing -> not a concurrency cap. The
//     comp_tile fma+store interleave makes every tile's compute redefine
//     the store-data regs (z) while nt-stores are outstanding -> WAR forces
//     a vmcnt wait on store retirement (in-order!) -> DRAM write latency
//     sits on every wave's serial critical path.
// R6: decouple stores from the critical path:
//     - 4-stage rotation bufA..D, prefetch distance 4 tiles (UNROLL=8):
//       loads are always issued BEFORE the same sub-step's stores, so any
//       future load-wait has only loads older than it (stores never gate).
//     - dedicated zA..zD output regs per stage: store-data regs not
//       redefined until 4 sub-steps (~400+ cyc) after store issue -> WAR
//       wait pre-satisfied.
//     - sched_barrier(0) after each load phase pins issue order so LLVM
//       cannot re-fold the pipeline (R5's VGPR=24 proves it does).
//     Outstanding VMEM <= 56 < vmcnt cap 63. VGPR ~80-90 -> 4+ waves/SIMD.

#define LAM   0.95f
#define CHUNK 128
#define WARM  128
#define UNROLL 8

constexpr int B  = 16;
constexpr int L  = 8192;
constexpr int K  = 256;
constexpr int G  = L / CHUNK;   // 64 chunks per batch

__global__ __launch_bounds__(256) void ewma_kernel(const float* __restrict__ x,
                                                   float* __restrict__ out) {
    const int wib  = (int)(threadIdx.x >> 6);     // K-slice 0..3 within block
    const int lane = threadIdx.x & 63;
    const int j    = blockIdx.x & (G - 1);        // chunk index
    const int b    = blockIdx.x >> 6;             // batch
    const int s    = j * CHUNK;                   // stored-region start
    const int t0   = (j == 0) ? 0 : (s - WARM);   // scan start (warm-up)

    const long chan = (long)b * L * K + wib * 64 + lane;  // this lane's channel
    const float* __restrict__ pin  = x   + chan + (long)t0 * K;
    float*       __restrict__ pout = out + chan + (long)t0 * K;

    const float c = 1.0f - LAM;
    float z = 0.f;

    const int total      = (s + CHUNK) - t0;      // 128 (chunk 0) or 256
    const int tiles      = total / UNROLL;        // 16 or 32 — divisible by 4
    const int warm_tiles = (s - t0) / UNROLL;     // 0 or 16

    float bufA[UNROLL], bufB[UNROLL], bufC[UNROLL], bufD[UNROLL];
    float zA[UNROLL],   zB[UNROLL],   zC[UNROLL],   zD[UNROLL];

    auto load_tile = [&](float (&buf)[UNROLL], int t) {
        const float* __restrict__ p = pin + (long)t * UNROLL * K;
        #pragma unroll
        for (int u = 0; u < UNROLL; ++u) buf[u] = p[(long)u * K];
    };

    auto comp_tile = [&](float (&buf)[UNROLL], float (&zb)[UNROLL]) {
        #pragma unroll
        for (int u = 0; u < UNROLL; ++u) {
            z = fmaf(LAM, z, c * buf[u]);
            zb[u] = z;
        }
    };

    auto store_tile = [&](float (&zb)[UNROLL], int t) {
        if (t < warm_tiles) return;               // wave-uniform
        float* __restrict__ p = pout + (long)t * UNROLL * K;
        #pragma unroll
        for (int u = 0; u < UNROLL; ++u)
            __builtin_nontemporal_store(zb[u], &p[(long)u * K]);
    };

    // Prologue: 4 tiles in flight (32 loads, 8 KB/wave).
    load_tile(bufA, 0);
    load_tile(bufB, 1);
    load_tile(bufC, 2);
    load_tile(bufD, 3);
    __builtin_amdgcn_sched_barrier(0);

    for (int t = 0; t < tiles; t += 4) {
        comp_tile(bufA, zA);
        if (t + 4 < tiles) load_tile(bufA, t + 4);
        __builtin_amdgcn_sched_barrier(0);
        store_tile(zA, t);

        comp_tile(bufB, zB);
        if (t + 5 < tiles) load_tile(bufB, t + 5);
        __builtin_amdgcn_sched_barrier(0);
        store_tile(zB, t + 1);

        comp_tile(bufC, zC);
        if (t + 6 < tiles) load_tile(bufC, t + 6);
        __builtin_amdgcn_sched_barrier(0);
        store_tile(zC, t + 2);

        comp_tile(bufD, zD);
        if (t + 7 < tiles) load_tile(bufD, t + 7);
        __builtin_amdgcn_sched_barrier(0);
        store_tile(zD, t + 3);
    }
}

extern "C" void kernel_launch(void* const* d_in, const int* in_sizes, int n_in,
                              void* d_out, int out_size, void* d_ws, size_t ws_size,
                              hipStream_t stream) {
    const float* x = (const float*)d_in[0];
    float* out = (float*)d_out;

    const int blocks = B * G;            // 1024 blocks (one per (b,chunk))
    hipLaunchKernelGGL(ewma_kernel, dim3(blocks), dim3(256), 0, stream, x, out);
}

// Round 4
// 247.728 us; speedup vs baseline: 1.0190x; 1.0190x over previous
//
#include <hip/hip_runtime.h>

// EWMA scan z_t = lam*z_{t-1} + (1-lam)*x_t over [B,L,K], chunk-parallel with
// 128-step warm-up (error <= lam^129 * max|z| ~ 1e-3 << 1.7e-2 threshold).
//
// R4 FAILED: CHUNK 128->32: occupancy 9->33% but FETCH 130->300 MB -> 130us.
// R5 NEUTRAL: K-split 4 (16 waves/CU, 1x traffic) -> 95us, 2.8 TB/s, VGPR=24.
// R6 NEUTRAL: 4-stage VGPR pipeline + sched_barrier -> 99us, VGPR=36: the
//     register allocator collapses every VGPR-resident pipeline (loads sunk
//     next to uses). Stores were never the long pole (store vmcnt retires at
//     L2-accept, not DRAM). Surviving theory: actual posted read depth is
//     ~1-2 loads/wave; under loaded latency (~2000cy) we need ~20KB/CU in
//     flight and never post it.
// R7: take depth away from the compiler entirely: LDS-DMA ring via
//     __builtin_amdgcn_global_load_lds (zero VGPR liveness -> nothing to
//     collapse). Private per-wave 2-slot ring, 16 steps/tile, 256B/step.
//     32 loads (8KB) in flight per wave BY CONSTRUCTION = 128KB/CU posted
//     reads. Hand-counted s_waitcnt vmcnt(N) (T4 idiom, never 0):
//       younger(tile i) = 16 loads(i+1) + 16 stores(i-1)
//       -> vmcnt(16) for warm/first/last segments, vmcnt(32) steady.
//     No barriers (ring is wave-private). sched_barrier(0) after each wait
//     pins ordering (guide rule #18). Slot overwrite is race-free: DMA
//     return latency (>=500cy) >> ds_read completion (~120cy).

#define LAM    0.95f
#define CHUNK  128
#define WARM   128
#define TSTEPS 16

constexpr int B = 16;
constexpr int L = 8192;
constexpr int K = 256;
constexpr int G = L / CHUNK;    // 64 chunks per batch

typedef const __attribute__((address_space(1))) unsigned int gu32;
typedef __attribute__((address_space(3)))       unsigned int lu32;

#define WAITV(N)                                                   \
    do {                                                           \
        asm volatile("s_waitcnt vmcnt(" #N ")" ::: "memory");      \
        __builtin_amdgcn_sched_barrier(0);                         \
    } while (0)

__global__ __launch_bounds__(256) void ewma_kernel(const float* __restrict__ x,
                                                   float* __restrict__ out) {
    __shared__ float lds[4][2][TSTEPS][64];       // 32 KB: [wave][slot][step][lane]

    const int wib  = (int)(threadIdx.x >> 6);     // K-slice 0..3 within block
    const int lane = threadIdx.x & 63;
    const int j    = blockIdx.x & (G - 1);        // chunk index
    const int b    = blockIdx.x >> 6;             // batch
    const int s    = j * CHUNK;                   // stored-region start
    const int t0   = (j == 0) ? 0 : (s - WARM);   // scan start (warm-up)

    const long chan = (long)b * L * K + wib * 64 + lane;  // this lane's channel
    const float* __restrict__ pin  = x   + chan + (long)t0 * K;
    float*       __restrict__ pout = out + chan + (long)t0 * K;

    const float c = 1.0f - LAM;
    float z = 0.f;

    const int total      = (s + CHUNK) - t0;      // 128 (chunk 0) or 256
    const int NT         = total / TSTEPS;        // 8 or 16 tiles
    const int warm_tiles = (s - t0) / TSTEPS;     // 0 or 8

    // Issue one tile's worth of fire-and-forget DMA loads (16 x 256B).
    auto stage = [&](int tile) {
        const float* p = pin + (long)tile * TSTEPS * K;
        lu32* lp = (lu32*)&lds[wib][tile & 1][0][0];   // wave-uniform base
        #pragma unroll
        for (int u = 0; u < TSTEPS; ++u)
            __builtin_amdgcn_global_load_lds((gu32*)(p + (long)u * K),
                                             lp + (long)u * 64, 4, 0, 0);
    };

    // Consume a tile from its LDS slot: 16 serial fma steps (+ nt stores).
    auto consume = [&](int tile) {
        const bool st = (tile >= warm_tiles);     // wave-uniform
        float* p = pout + (long)tile * TSTEPS * K;
        #pragma unroll
        for (int u = 0; u < TSTEPS; ++u) {
            const float xv = lds[wib][tile & 1][u][lane];
            z = fmaf(LAM, z, c * xv);
            if (st) __builtin_nontemporal_store(z, &p[(long)u * K]);
        }
    };

    stage(0);
    stage(1);

    // Segment 1: younger ops at wait = 16 loads only (no stores issued among
    // the 16..32 youngest: tiles < warm_tiles don't store). Covers i=0 and
    // all warm tiles, plus the first stored tile (its PREVIOUS tile is warm).
    const int W1 = warm_tiles + 1;
    int i = 0;
    for (; i < W1; ++i) {
        WAITV(16);
        consume(i);
        if (i + 2 < NT) stage(i + 2);
    }
    // Segment 2 (steady state): younger = 16 loads(i+1) + 16 stores(i-1).
    for (; i < NT - 1; ++i) {
        WAITV(32);
        consume(i);
        if (i + 2 < NT) stage(i + 2);
    }
    // Last tile: younger = 16 stores(NT-2) only (no loads after tile NT-1).
    WAITV(16);
    consume(NT - 1);
}

extern "C" void kernel_launch(void* const* d_in, const int* in_sizes, int n_in,
                              void* d_out, int out_size, void* d_ws, size_t ws_size,
                              hipStream_t stream) {
    const float* x = (const float*)d_in[0];
    float* out = (float*)d_out;

    const int blocks = B * G;            // 1024 blocks (one per (b,chunk))
    hipLaunchKernelGGL(ewma_kernel, dim3(blocks), dim3(256), 0, stream, x, out);
}